// Round 1
// baseline (569.544 us; speedup 1.0000x reference)
//
#include <hip/hip_runtime.h>

using half8   = __attribute__((ext_vector_type(8))) _Float16;
using floatx4 = __attribute__((ext_vector_type(4))) float;

namespace {
constexpr int S = 196, D = 512, C = 1006, Cpad = 1024;
constexpr int CB  = 16;     // block c-tile
constexpr int BK  = 64;     // k-chunk (8 chunks, 2 MFMA k-steps each)
constexpr int TPB = 512;    // r5: 8 waves, FULL e=512 per block -> tanh computed once (was 2x via et split)
constexpr int SCH = 2;      // s-chunks of 98 -> grid 64*2*2 = 256 = exactly 1 block/CU
constexpr int RS  = 64;     // row stride (halfs); 16B-seg XOR swizzle
constexpr float KTANH = 2.885390082f;    // 2/ln2 folded into img staging
constexpr float INVK  = 0.34657359028f;  // ln2/2 to recover raw img
constexpr float LOG2E = 1.44269504f;     // folded into W at prep: acc = log2e*feat

// ws layout (bytes)
constexpr size_t W16_BYTES   = (size_t)D * D * 2;             // 512 KB swizzled W
constexpr size_t LA_OFF      = W16_BYTES;
constexpr size_t SLICE_ELEMS = (size_t)2 * Cpad * D;          // 4 MB (floats)
constexpr size_t SL_BYTES    = (size_t)SCH * SLICE_ELEMS * 4; // 8 MB per set
constexpr size_t SLICE_NEED  = LA_OFF + 2 * SL_BYTES;         // ~16.5 MB (< prior 24.5 -> still slice)
constexpr size_t L_BYTES     = SLICE_ELEMS * 4;

// swizzled offset (halfs): row stride 64, 16B-seg XOR'd by row&7 (conflict-free frag reads)
__device__ __forceinline__ int sw_off(int row, int seg) {
    return row * RS + ((seg ^ (row & 7)) << 3);
}

__device__ __forceinline__ _Float16 tanh_ps(float y) {
    // y = (2/ln2)*x; tanh(x) = 1 - 2/(exp2(y)+1); saturates correctly
    float e = __builtin_amdgcn_exp2f(y);
    return (_Float16)(1.0f - 2.0f * __builtin_amdgcn_rcpf(e + 1.0f));
}

__device__ __forceinline__ half8 tanh8(floatx4 i0, floatx4 i1, floatx4 w0, floatx4 w1) {
    half8 t;
    t[0] = tanh_ps(i0[0] * w0[0]); t[1] = tanh_ps(i0[1] * w0[1]);
    t[2] = tanh_ps(i0[2] * w0[2]); t[3] = tanh_ps(i0[3] * w0[3]);
    t[4] = tanh_ps(i1[0] * w1[0]); t[5] = tanh_ps(i1[1] * w1[1]);
    t[6] = tanh_ps(i1[2] * w1[2]); t[7] = tanh_ps(i1[3] * w1[3]);
    return t;
}

// Pre-swizzle fc3_w*log2e into the per-chunk image (8 chunks of 512 rows x 8 16B-segs).
// r5: the main kernel now reads B-fragments DIRECTLY from this L2-resident image
// (identical bytes it previously ds_read from Wc) -- no W LDS staging at all.
__global__ void prep_w16sw(const float* __restrict__ fw, _Float16* __restrict__ W16sw) {
    int id = blockIdx.x * blockDim.x + threadIdx.x;    // 32768 segs
    int kki = id >> 12;
    int r   = (id >> 3) & 511;
    int j   = id & 7;
    const float* src = fw + (size_t)r * D + kki * BK + j * 8;
    floatx4 v0 = *(const floatx4*)src;
    floatx4 v1 = *(const floatx4*)(src + 4);
    half8 h;
    h[0] = (_Float16)(v0[0] * LOG2E); h[1] = (_Float16)(v0[1] * LOG2E);
    h[2] = (_Float16)(v0[2] * LOG2E); h[3] = (_Float16)(v0[3] * LOG2E);
    h[4] = (_Float16)(v1[0] * LOG2E); h[5] = (_Float16)(v1[1] * LOG2E);
    h[6] = (_Float16)(v1[2] * LOG2E); h[7] = (_Float16)(v1[3] * LOG2E);
    *(half8*)&W16sw[((size_t)kki << 15) + r * RS + ((j ^ (r & 7)) << 3)] = h;
}

__global__ __launch_bounds__(TPB, 2) void semdec_mfma(
    const float* __restrict__ img, const float* __restrict__ word,
    const _Float16* __restrict__ W16sw,
    float* __restrict__ lbase, float* __restrict__ abase, int use_slice)
{
    // r5 LDS: 24 KB total (was 48 KB). W no longer staged.
    __shared__ __align__(16) _Float16 Tc[2][4 * CB * RS]; // 2 x 8 KB, dbuf: T(k+1) built while MFMA(k) runs
    __shared__ __align__(16) float imgS[4][D];            // 8 KB, pre-scaled by 2/ln2

    const int ct = blockIdx.x;           // 0..63 c-tile
    const int b  = blockIdx.y;           // 0..1
    const int sc = blockIdx.z;           // 0..1  (s-chunks of 98)

    const int tid  = threadIdx.x;
    const int lane = tid & 63;
    const int wv   = tid >> 6;           // wave 0..7 = 64-wide e-slot
    const int l15  = lane & 15;
    const int quad = lane >> 4;

    const int c0 = ct * CB;

    // T-stage mapping: thread -> (siT, ciT, segT); 8 tanh per thread per chunk
    const int siT  = tid >> 7;           // 0..3 (wave-uniform)
    const int ciT  = (tid >> 3) & 15;
    const int segT = tid & 7;
    int cgT = c0 + ciT; if (cgT > C - 1) cgT = C - 1;   // clamp pad rows
    const float* wordRowT = word + (size_t)cgT * D + segT * 8;

    floatx4 lacc[4], aacc[4];            // 32 VGPR softmax sums
    #pragma unroll
    for (int ej = 0; ej < 4; ++ej) {
        lacc[ej] = (floatx4){0.f, 0.f, 0.f, 0.f};
        aacc[ej] = (floatx4){0.f, 0.f, 0.f, 0.f};
    }

    const float* imgB = img + (size_t)b * S * D;
    const int s_base = sc * 98;                       // 0 or 98
    constexpr int NPASS = 25;                         // 24x4s + 1x2s = 98

    // cyclic word prefetch: wc = chunk used by the NEXT T compute; wn = one further ahead
    floatx4 wc0 = *(const floatx4*)(wordRowT);
    floatx4 wc1 = *(const floatx4*)(wordRowT + 4);
    floatx4 wn0 = *(const floatx4*)(wordRowT + BK);
    floatx4 wn1 = *(const floatx4*)(wordRowT + BK + 4);

    for (int pr = 0; pr < NPASS; ++pr) {
        const int s0 = s_base + pr * 4;
        const int slim = (pr == NPASS - 1) ? 2 : 4;

        __syncthreads();  // prior pass epilogue done reading imgS
        {   // stage imgS: exactly 1 float4/thread (4 rows x 512 f32)
            int si = tid >> 7, pos = (tid & 127) << 2;
            int srow = s0 + si; if (srow > S - 1) srow = S - 1;  // tail clamp (finite, unused rows)
            floatx4 v = *(const floatx4*)&imgB[(size_t)srow * D + pos];
            *(floatx4*)&imgS[si][pos] = v * KTANH;
        }
        __syncthreads();  // imgS visible

        // pass-start bubble: T(chunk 0) -> Tc[0]  (word(0) is in wc from prev pass's kk=6 shift)
        {
            const float* ip = &imgS[siT][segT * 8];
            floatx4 i0 = *(const floatx4*)ip;
            floatx4 i1 = *(const floatx4*)(ip + 4);
            *(half8*)&Tc[0][sw_off(siT * CB + ciT, segT)] = tanh8(i0, i1, wc0, wc1);
        }
        wc0 = wn0; wc1 = wn1;  // wc <- word(1)
        __syncthreads();       // Tc[0] visible

        floatx4 acc[4][4];     // [si][ej] 64 AGPR
        #pragma unroll
        for (int si = 0; si < 4; ++si)
            #pragma unroll
            for (int ej = 0; ej < 4; ++ej)
                acc[si][ej] = (floatx4){0.f, 0.f, 0.f, 0.f};

        for (int kk = 0; kk < 8; ++kk) {
            const int p = kk & 1;
            const _Float16* Tcp = Tc[p];

            // --- B frags straight from the L2-resident swizzled W image (issued first:
            //     L2 latency hides under af reads + tanh). Per instr: 16 rows x 1 full
            //     64B line each -> line-perfect.
            const _Float16* wgk = W16sw + ((size_t)kk << 15);
            half8 bf[2][4], af[2][4];
            #pragma unroll
            for (int k2 = 0; k2 < 2; ++k2)
                #pragma unroll
                for (int ej = 0; ej < 4; ++ej)
                    bf[k2][ej] = *(const half8*)&wgk[sw_off(wv * 64 + ej * 16 + l15, (k2 << 2) + quad)];

            // --- word prefetch for chunk (kk+2)&7 (cyclic across the pass boundary)
            {
                const int kc = ((kk + 2) & 7) * BK;
                wn0 = *(const floatx4*)(wordRowT + kc);
                wn1 = *(const floatx4*)(wordRowT + kc + 4);
            }

            // --- A frags of chunk kk from Tc[p]
            #pragma unroll
            for (int k2 = 0; k2 < 2; ++k2)
                #pragma unroll
                for (int si = 0; si < 4; ++si)
                    af[k2][si] = *(const half8*)&Tcp[sw_off(si * CB + l15, (k2 << 2) + quad)];

            // --- pipelined T(kk+1) -> Tc[p^1] (skipped at kk==7; next pass's bubble does chunk 0)
            if (kk < 7) {
                const float* ip = &imgS[siT][((kk + 1) << 6) + segT * 8];
                floatx4 i0 = *(const floatx4*)ip;
                floatx4 i1 = *(const floatx4*)(ip + 4);
                *(half8*)&Tc[p ^ 1][sw_off(siT * CB + ciT, segT)] = tanh8(i0, i1, wc0, wc1);
                wc0 = wn0; wc1 = wn1;
            }

            // --- MFMA: 2 k-steps of 32; scheduler may interleave with the tanh stream above
            #pragma unroll
            for (int k2 = 0; k2 < 2; ++k2)
                #pragma unroll
                for (int si = 0; si < 4; ++si)
                    #pragma unroll
                    for (int ej = 0; ej < 4; ++ej)
                        acc[si][ej] = __builtin_amdgcn_mfma_f32_16x16x32_f16(
                            af[k2][si], bf[k2][ej], acc[si][ej], 0, 0, 0);

            __syncthreads();  // Tc[p^1] writes visible; Tc[p] reads done before next overwrite
        }

        // --- online softmax accumulate; acc = log2e*feat so exp2(acc) = exp(feat)
        #pragma unroll
        for (int si = 0; si < 4; ++si) {
            if (si >= slim) break;
            #pragma unroll
            for (int ej = 0; ej < 4; ++ej) {
                float ie = imgS[si][wv * 64 + ej * 16 + l15] * INVK;
                #pragma unroll
                for (int r = 0; r < 4; ++r) {
                    float ev = __builtin_amdgcn_exp2f(acc[si][ej][r]);
                    lacc[ej][r] += ev;
                    aacc[ej][r] += ie * ev;
                }
            }
        }
    }

    // --- writeout (C/D layout: col=lane&15 -> e, row=quad*4+r -> c)
    if (use_slice) {
        float* lsl = lbase + (size_t)sc * SLICE_ELEMS;
        float* asl = abase + (size_t)sc * SLICE_ELEMS;
        #pragma unroll
        for (int r = 0; r < 4; ++r) {
            int cg = c0 + quad * 4 + r;
            #pragma unroll
            for (int ej = 0; ej < 4; ++ej) {
                int eg = wv * 64 + ej * 16 + l15;
                size_t o = ((size_t)b * Cpad + cg) * D + eg;
                lsl[o] = lacc[ej][r];
                asl[o] = aacc[ej][r];
            }
        }
    } else {
        #pragma unroll
        for (int r = 0; r < 4; ++r) {
            int cg = c0 + quad * 4 + r;
            #pragma unroll
            for (int ej = 0; ej < 4; ++ej) {
                int eg = wv * 64 + ej * 16 + l15;
                atomicAdd(&lbase[((size_t)b * Cpad + cg) * D + eg], lacc[ej][r]);
                if (cg < C)
                    atomicAdd(&abase[((size_t)b * C + cg) * D + eg], aacc[ej][r]);
            }
        }
    }
}

__global__ void finalize_k(const float* __restrict__ lbase, const float* __restrict__ abase,
                           float* __restrict__ out, int use_slice) {
    int o = blockIdx.x * blockDim.x + threadIdx.x;
    if (o >= 2 * C * D) return;
    int b = o / (C * D);
    int rem = o - b * (C * D);
    int c = rem >> 9;
    int e = rem & (D - 1);
    size_t p = ((size_t)b * Cpad + c) * D + e;
    if (use_slice) {
        float l = 0.f, a = 0.f;
        #pragma unroll
        for (int scn = 0; scn < SCH; ++scn) {
            l += lbase[(size_t)scn * SLICE_ELEMS + p];
            a += abase[(size_t)scn * SLICE_ELEMS + p];
        }
        out[o] = a / l;
    } else {
        out[o] = out[o] / lbase[p];
    }
}

} // namespace

extern "C" void kernel_launch(void* const* d_in, const int* in_sizes, int n_in,
                              void* d_out, int out_size, void* d_ws, size_t ws_size,
                              hipStream_t stream) {
    const float* img  = (const float*)d_in[0];
    const float* word = (const float*)d_in[1];
    const float* fw   = (const float*)d_in[2];
    // d_in[3] = fc3_b: constant over softmax axis s -> cancels exactly.
    float* out = (float*)d_out;
    char* ws = (char*)d_ws;

    _Float16* W16sw = (_Float16*)ws;
    const int use_slice = (ws_size >= SLICE_NEED) ? 1 : 0;

    hipLaunchKernelGGL(prep_w16sw, dim3(128), dim3(256), 0, stream, fw, W16sw);

    float *lbase, *abase;
    if (use_slice) {
        lbase = (float*)(ws + LA_OFF);
        abase = (float*)(ws + LA_OFF + SL_BYTES);
    } else {
        lbase = (float*)(ws + LA_OFF);
        abase = out;
        hipMemsetAsync(lbase, 0, L_BYTES, stream);
        hipMemsetAsync(out, 0, (size_t)2 * C * D * 4, stream);
    }

    hipLaunchKernelGGL(semdec_mfma, dim3(64, 2, SCH), dim3(TPB), 0, stream,
                       img, word, W16sw, lbase, abase, use_slice);

    hipLaunchKernelGGL(finalize_k, dim3((2 * C * D + 255) / 256), dim3(256), 0, stream,
                       lbase, abase, out, use_slice);
}